// Round 1
// baseline (26.306 us; speedup 1.0000x reference)
//
#include <hip/hip_runtime.h>

// UserEmbedding: out[b, d] = W[d, x[b]]
//   x: [16384] int32 indices in [0, 1e6)
//   W: [64, 1_000_000] float32 row-major
//   out: [16384, 64] float32
//
// One thread per output element. tid = b*64 + d (d = low 6 bits), so each
// 64-lane wave handles one batch element b: one broadcast x[b] load, 64
// scattered 4B reads of W at 4MB stride (inherently uncoalesced — each read
// is its own HBM line), and one fully-coalesced 256B store.

#define NUM_USERS 1000000
#define DIM 64
#define BATCH 16384

__global__ __launch_bounds__(256) void UserEmbedding_61873298866785_kernel(
    const int* __restrict__ x,
    const float* __restrict__ W,
    float* __restrict__ out) {
    const int tid = blockIdx.x * blockDim.x + threadIdx.x;  // 0 .. BATCH*DIM-1
    const int b = tid >> 6;   // batch element (uniform within a wave)
    const int d = tid & 63;   // embedding dim (lane id)
    const int u = x[b];       // broadcast within the wave
    out[tid] = W[(size_t)d * NUM_USERS + (size_t)u];
}

extern "C" void kernel_launch(void* const* d_in, const int* in_sizes, int n_in,
                              void* d_out, int out_size, void* d_ws, size_t ws_size,
                              hipStream_t stream) {
    const int* x = (const int*)d_in[0];
    const float* W = (const float*)d_in[1];
    float* out = (float*)d_out;

    const int total = BATCH * DIM;          // 1,048,576
    const int block = 256;
    const int grid = total / block;         // 4096
    UserEmbedding_61873298866785_kernel<<<grid, block, 0, stream>>>(x, W, out);
}